// Round 7
// baseline (431.670 us; speedup 1.0000x reference)
//
#include <hip/hip_runtime.h>
#include <math.h>

#define NN 50000
#define DD 128
#define NCLS 40
#define EPSV 1e-8f

__device__ __forceinline__ float waveReduceSum(float v) {
    for (int off = 32; off > 0; off >>= 1) v += __shfl_xor(v, off, 64);
    return v;
}

// broadcast lane j's value to all lanes via SGPR (readlane): zero-latency FMA operand
__device__ __forceinline__ float bcast(float v, int j) {
    return __int_as_float(__builtin_amdgcn_readlane(__float_as_int(v), j));
}

// ---------------- CSR build ----------------

__global__ void hist_kernel(const int* __restrict__ erow, int* __restrict__ cnt, int E) {
    for (int e = blockIdx.x * blockDim.x + threadIdx.x; e < E; e += gridDim.x * blockDim.x)
        atomicAdd(&cnt[erow[e]], 1);
}

__global__ void scan1_kernel(const int* __restrict__ cnt, int* __restrict__ rs,
                             int* __restrict__ bsum, int n) {
    __shared__ int sdata[256];
    int tid = threadIdx.x;
    int gid = blockIdx.x * 256 + tid;
    int v = (gid < n) ? cnt[gid] : 0;
    sdata[tid] = v;
    __syncthreads();
    for (int off = 1; off < 256; off <<= 1) {
        int t = (tid >= off) ? sdata[tid - off] : 0;
        __syncthreads();
        sdata[tid] += t;
        __syncthreads();
    }
    if (gid < n) rs[gid] = sdata[tid] - v;
    if (tid == 255) bsum[blockIdx.x] = sdata[255];
}

__global__ void scan2_kernel(int* __restrict__ bsum, int nb) {
    __shared__ int sdata[256];
    int tid = threadIdx.x;
    int v = (tid < nb) ? bsum[tid] : 0;
    sdata[tid] = v;
    __syncthreads();
    for (int off = 1; off < 256; off <<= 1) {
        int t = (tid >= off) ? sdata[tid - off] : 0;
        __syncthreads();
        sdata[tid] += t;
        __syncthreads();
    }
    if (tid < nb) bsum[tid] = sdata[tid] - v;
}

__global__ void scan3_kernel(int* __restrict__ rs, const int* __restrict__ bsum, int n, int E) {
    int gid = blockIdx.x * 256 + threadIdx.x;
    if (gid < n) rs[gid] += bsum[blockIdx.x];
    else if (gid == n) rs[n] = E;
}

__global__ void fill_kernel(const int* __restrict__ erow, const int* __restrict__ ecol,
                            const float* __restrict__ ew, int* __restrict__ pos,
                            int* __restrict__ ecol_s, float* __restrict__ ew_s, int E) {
    for (int e = blockIdx.x * blockDim.x + threadIdx.x; e < E; e += gridDim.x * blockDim.x) {
        int r = erow[e];
        int p = atomicAdd(&pos[r], 1);
        ecol_s[p] = ecol[e];
        ew_s[p] = ew[e];
    }
}

// ---------------- fused linears ----------------
// 12 rows/wave, x rows in REGISTERS (lane l holds elements 2l,2l+1).
// x[k] broadcast via readlane (SGPR operand, no LDS, no latency).
// W transposed in LDS stride 129: staging writes hit consecutive banks
// (conflict-free), reads are float2-contiguous. LDS 66KB -> 2 blocks/CU.
// PREEXP=1: X is node_feat (N,127); apply expmap0 first.
// PREEXP=0: X is (N,128) raw agg sums; lorentz-normalize + relu first.
#define RPW 12
template <int PREEXP>
__global__ __launch_bounds__(512, 4) void linear_lorentz(
    const float* __restrict__ X, const float* __restrict__ W,
    const float* __restrict__ bias, const float* __restrict__ logs,
    float* __restrict__ out, int n)
{
    __shared__ float Wt[127 * 129 + 128];    // Wt[k*129+i] = W[i*128+k], 66KB
    int tid = threadIdx.x;
    int wid = tid >> 6, lane = tid & 63;
    // stage W transposed: consecutive tid -> consecutive k -> consecutive banks
    for (int idx = tid; idx < 128 * 128; idx += 512) {
        int i = idx >> 7, k = idx & 127;     // global read coalesced
        Wt[k * 129 + i] = W[idx];
    }
    __syncthreads();
    float2 bv = *(const float2*)(bias + 2 * lane);
    float sval = fminf(expf(logs[0]), 10.f);
    int nslabs = (n + RPW - 1) / RPW;        // 4167
    for (int slab = blockIdx.x * 8 + wid; slab < nslabs; slab += gridDim.x * 8) {
        int row0 = slab * RPW;
        // ---- preprocess RPW rows into registers ----
        float2 xv[RPW];
        #pragma unroll
        for (int r = 0; r < RPW; ++r) {
            int row = row0 + r;
            if (row >= n) { xv[r] = make_float2(0.f, 0.f); continue; }
            if (PREEXP) {
                const float* src = X + (long)row * 127;
                float u0 = src[2 * lane];
                float u1 = (2 * lane + 1 < 127) ? src[2 * lane + 1] : 0.f;
                float ss = waveReduceSum(u0 * u0 + u1 * u1);
                float nrm = fmaxf(sqrtf(ss), EPSV);
                float ex = expf(nrm), exn = 1.f / ex;
                float ch = 0.5f * (ex + exn);
                float coef = (0.5f * (ex - exn)) / nrm;
                // x[2l] = coef*u[2l-1] (prev lane's u1), x[0] = ch; x[2l+1] = coef*u[2l]
                float u1p = __shfl(u1, (lane + 63) & 63, 64);
                xv[r].x = (lane == 0) ? ch : coef * u1p;
                xv[r].y = coef * u0;
            } else {
                float2 e = *(const float2*)(X + (long)row * 128 + 2 * lane);
                float t0 = __shfl(e.x, 0, 64);
                float ss = waveReduceSum(e.x * e.x + e.y * e.y);
                float neg_inner = 2.f * t0 * t0 - ss;
                float inv = 1.f / sqrtf(fmaxf(fabsf(neg_inner), EPSV));
                e.x = fmaxf(e.x * inv, 0.f);
                e.y = fmaxf(e.y * inv, 0.f);
                xv[r] = e;
            }
        }
        // ---- GEMM: lane computes cols 2l,2l+1; x[k] via readlane broadcast ----
        float2 acc[RPW];
        #pragma unroll
        for (int r = 0; r < RPW; ++r) acc[r] = make_float2(0.f, 0.f);
        #pragma unroll 8
        for (int j = 0; j < 64; ++j) {       // k = 2j, 2j+1
            float2 wA = *(const float2*)(Wt + (2 * j) * 129 + 2 * lane);
            float2 wB = *(const float2*)(Wt + (2 * j + 1) * 129 + 2 * lane);
            #pragma unroll
            for (int r = 0; r < RPW; ++r) {
                float xa = bcast(xv[r].x, j);
                float xb = bcast(xv[r].y, j);
                acc[r].x = fmaf(xb, wB.x, fmaf(xa, wA.x, acc[r].x));
                acc[r].y = fmaf(xb, wB.y, fmaf(xa, wA.y, acc[r].y));
            }
        }
        // ---- lorentz epilogue per row ----
        #pragma unroll
        for (int r = 0; r < RPW; ++r) {
            int row = row0 + r;
            float ax = acc[r].x + bv.x;
            float ay = acc[r].y + bv.y;
            float t0 = __shfl(ax, 0, 64);
            float ssq = waveReduceSum(ax * ax + ay * ay);
            float timev = sval / (1.f + expf(-t0)) + 1.5f;
            float sq = fmaxf(ssq - t0 * t0, EPSV);
            float fac = sqrtf(fmaxf((timev * timev - 1.f) / sq, EPSV));
            if (row < n) {
                float2 o;
                o.x = (lane == 0) ? timev : ax * fac;
                o.y = ay * fac;
                *(float2*)(out + (long)row * 128 + 2 * lane) = o;
            }
        }
    }
}

// ---------------- CSR gather (agg) ----------------

__global__ void gather_kernel(const float* __restrict__ X, const int* __restrict__ rs,
                              const int* __restrict__ ecol_s, const float* __restrict__ ew_s,
                              float* __restrict__ S, int n)
{
    int wid = threadIdx.x >> 6, lane = threadIdx.x & 63;
    for (int row = blockIdx.x * 4 + wid; row < n; row += gridDim.x * 4) {
        int beg = rs[row], end = rs[row + 1];
        float2 acc = {0.f, 0.f};
        for (int base = beg; base < end; base += 64) {
            int idx = base + lane;
            int colv = (idx < end) ? ecol_s[idx] : 0;
            float wv = (idx < end) ? ew_s[idx] : 0.f;
            int cnt = min(64, end - base);
            for (int j = 0; j < cnt; ++j) {
                int c = __shfl(colv, j, 64);
                float wj = __shfl(wv, j, 64);
                float2 xv = *(const float2*)(X + (long)c * 128 + 2 * lane);
                acc.x = fmaf(wj, xv.x, acc.x);
                acc.y = fmaf(wj, xv.y, acc.y);
            }
        }
        *(float2*)(S + (long)row * 128 + 2 * lane) = acc;
    }
}

// agg2 + lorentz-normalize + sign-flip + logits, fused
__global__ void gather_logits_kernel(
    const float* __restrict__ X, const int* __restrict__ rs,
    const int* __restrict__ ecol_s, const float* __restrict__ ew_s,
    const float* __restrict__ cls, const float* __restrict__ cbias,
    float* __restrict__ outp, int n)
{
    __shared__ float clsS[NCLS * 129];
    __shared__ float cbS[NCLS];
    __shared__ float xsrow[4][128];
    int tid = threadIdx.x;
    for (int idx = tid; idx < NCLS * 128; idx += 256) {
        int c = idx >> 7, k = idx & 127;
        clsS[c * 129 + k] = cls[idx];
    }
    if (tid < NCLS) cbS[tid] = cbias[tid];
    __syncthreads();
    int wid = tid >> 6, lane = tid & 63;
    float* xs = xsrow[wid];
    for (int row = blockIdx.x * 4 + wid; row < n; row += gridDim.x * 4) {
        int beg = rs[row], end = rs[row + 1];
        float2 acc = {0.f, 0.f};
        for (int base = beg; base < end; base += 64) {
            int idx = base + lane;
            int colv = (idx < end) ? ecol_s[idx] : 0;
            float wv = (idx < end) ? ew_s[idx] : 0.f;
            int cnt = min(64, end - base);
            for (int j = 0; j < cnt; ++j) {
                int c = __shfl(colv, j, 64);
                float wj = __shfl(wv, j, 64);
                float2 xv = *(const float2*)(X + (long)c * 128 + 2 * lane);
                acc.x = fmaf(wj, xv.x, acc.x);
                acc.y = fmaf(wj, xv.y, acc.y);
            }
        }
        float t0 = __shfl(acc.x, 0, 64);
        float ss = waveReduceSum(acc.x * acc.x + acc.y * acc.y);
        float neg_inner = 2.f * t0 * t0 - ss;
        float inv = 1.f / sqrtf(fmaxf(fabsf(neg_inner), EPSV));
        float2 xv;
        xv.x = acc.x * inv;
        xv.y = acc.y * inv;
        if (lane == 0) xv.x = -xv.x;
        xs[2 * lane] = xv.x;
        xs[2 * lane + 1] = xv.y;
        if (lane < NCLS) {
            float dot = 0.f;
            #pragma unroll 8
            for (int k = 0; k < 128; ++k)
                dot = fmaf(xs[k], clsS[lane * 129 + k], dot);
            outp[(long)row * NCLS + lane] = 2.f + 2.f * dot + cbS[lane];
        }
    }
}

// ---------------- launch ----------------

extern "C" void kernel_launch(void* const* d_in, const int* in_sizes, int n_in,
                              void* d_out, int out_size, void* d_ws, size_t ws_size,
                              hipStream_t stream) {
    const float* node_feat = (const float*)d_in[0];
    const float* W1   = (const float*)d_in[1];
    const float* b1   = (const float*)d_in[2];
    const float* s1   = (const float*)d_in[3];
    const float* W2   = (const float*)d_in[4];
    const float* b2   = (const float*)d_in[5];
    const float* s2   = (const float*)d_in[6];
    const float* cls  = (const float*)d_in[7];
    const float* cb   = (const float*)d_in[8];
    const float* ew   = (const float*)d_in[9];
    const int*   erow = (const int*)d_in[10];
    const int*   ecol = (const int*)d_in[11];
    float* outp = (float*)d_out;

    const int n = NN;
    const int E = in_sizes[9];
    const int NBLK = (NN + 255) / 256;   // 196

    float* bufA   = (float*)d_ws;                       // NN*128
    float* bufB   = bufA + (size_t)NN * 128;            // NN*128
    int*   rs     = (int*)(bufB + (size_t)NN * 128);    // NN+1
    int*   pos    = rs + (NN + 1);                      // NN
    int*   bsum   = pos + NN;                           // <=256
    int*   ecol_s = bsum + 256;                         // E
    float* ew_s   = (float*)(ecol_s + E);               // E

    // CSR build
    (void)hipMemsetAsync(pos, 0, (size_t)NN * sizeof(int), stream);
    hist_kernel<<<2048, 256, 0, stream>>>(erow, pos, E);
    scan1_kernel<<<NBLK, 256, 0, stream>>>(pos, rs, bsum, n);
    scan2_kernel<<<1, 256, 0, stream>>>(bsum, NBLK);
    scan3_kernel<<<NBLK, 256, 0, stream>>>(rs, bsum, n, E);
    (void)hipMemcpyAsync(pos, rs, (size_t)NN * sizeof(int), hipMemcpyDeviceToDevice, stream);
    fill_kernel<<<2048, 256, 0, stream>>>(erow, ecol, ew, pos, ecol_s, ew_s, E);

    // pipeline
    linear_lorentz<1><<<512, 512, 0, stream>>>(node_feat, W1, b1, s1, bufA, n);  // expmap+L1
    gather_kernel<<<4096, 256, 0, stream>>>(bufA, rs, ecol_s, ew_s, bufB, n);    // agg1
    linear_lorentz<0><<<512, 512, 0, stream>>>(bufB, W2, b2, s2, bufA, n);       // norm+relu+L2
    gather_logits_kernel<<<4096, 256, 0, stream>>>(bufA, rs, ecol_s, ew_s, cls, cb, outp, n); // agg2+logits
}

// Round 8
// 386.593 us; speedup vs baseline: 1.1166x; 1.1166x over previous
//
#include <hip/hip_runtime.h>
#include <math.h>

#define NN 50000
#define DD 128
#define NCLS 40
#define EPSV 1e-8f

__device__ __forceinline__ float waveReduceSum(float v) {
    for (int off = 32; off > 0; off >>= 1) v += __shfl_xor(v, off, 64);
    return v;
}

// ---------------- CSR build ----------------

__global__ void hist_kernel(const int* __restrict__ erow, int* __restrict__ cnt, int E) {
    for (int e = blockIdx.x * blockDim.x + threadIdx.x; e < E; e += gridDim.x * blockDim.x)
        atomicAdd(&cnt[erow[e]], 1);
}

__global__ void scan1_kernel(const int* __restrict__ cnt, int* __restrict__ rs,
                             int* __restrict__ bsum, int n) {
    __shared__ int sdata[256];
    int tid = threadIdx.x;
    int gid = blockIdx.x * 256 + tid;
    int v = (gid < n) ? cnt[gid] : 0;
    sdata[tid] = v;
    __syncthreads();
    for (int off = 1; off < 256; off <<= 1) {
        int t = (tid >= off) ? sdata[tid - off] : 0;
        __syncthreads();
        sdata[tid] += t;
        __syncthreads();
    }
    if (gid < n) rs[gid] = sdata[tid] - v;
    if (tid == 255) bsum[blockIdx.x] = sdata[255];
}

__global__ void scan2_kernel(int* __restrict__ bsum, int nb) {
    __shared__ int sdata[256];
    int tid = threadIdx.x;
    int v = (tid < nb) ? bsum[tid] : 0;
    sdata[tid] = v;
    __syncthreads();
    for (int off = 1; off < 256; off <<= 1) {
        int t = (tid >= off) ? sdata[tid - off] : 0;
        __syncthreads();
        sdata[tid] += t;
        __syncthreads();
    }
    if (tid < nb) bsum[tid] = sdata[tid] - v;
}

__global__ void scan3_kernel(int* __restrict__ rs, const int* __restrict__ bsum, int n, int E) {
    int gid = blockIdx.x * 256 + threadIdx.x;
    if (gid < n) rs[gid] += bsum[blockIdx.x];
    else if (gid == n) rs[n] = E;
}

__global__ void fill_kernel(const int* __restrict__ erow, const int* __restrict__ ecol,
                            const float* __restrict__ ew, int* __restrict__ pos,
                            int* __restrict__ ecol_s, float* __restrict__ ew_s, int E) {
    for (int e = blockIdx.x * blockDim.x + threadIdx.x; e < E; e += gridDim.x * blockDim.x) {
        int r = erow[e];
        int p = atomicAdd(&pos[r], 1);
        ecol_s[p] = ecol[e];
        ew_s[p] = ew[e];
    }
}

// ---------------- W transpose (once per launch, 16K elements) ----------------
__global__ void transpose128(const float* __restrict__ W, float* __restrict__ Wt) {
    int idx = blockIdx.x * 256 + threadIdx.x;
    if (idx < 128 * 128) {
        int i = idx >> 7, k = idx & 127;
        Wt[k * 128 + i] = W[idx];     // read coalesced, write strided (tiny)
    }
}

// ---------------- fused linears ----------------
// 8 rows/wave. x slab per wave in LDS (uniform-address b128 broadcast reads).
// W pre-transposed in GLOBAL (Wt[k][i]): wave reads Wt[k][2l:2l+1] = 512
// contiguous bytes -> coalesced, L1/L2-hot (64KB shared by all waves).
// LDS 16KB/block (256 thr), VGPR<=64 -> up to 8 waves/SIMD.
// PREEXP=1: X is node_feat (N,127); apply expmap0 first.
// PREEXP=0: X is (N,128) raw agg sums; lorentz-normalize + relu first.
#define RPW 8
template <int PREEXP>
__global__ __launch_bounds__(256, 8) void linear_lorentz(
    const float* __restrict__ X, const float* __restrict__ Wt,
    const float* __restrict__ bias, const float* __restrict__ logs,
    float* __restrict__ out, int n)
{
    __shared__ float xrow[4][RPW * 128];     // 4 waves * 4KB = 16KB
    int tid = threadIdx.x;
    int wid = tid >> 6, lane = tid & 63;
    float2 bv = *(const float2*)(bias + 2 * lane);
    float sval = fminf(expf(logs[0]), 10.f);
    float* xbase = xrow[wid];                // wave-private
    const float* wcol = Wt + 2 * lane;       // this lane's 2 output cols
    int nslabs = (n + RPW - 1) / RPW;        // 6250
    for (int slab = blockIdx.x * 4 + wid; slab < nslabs; slab += gridDim.x * 4) {
        int row0 = slab * RPW;
        // ---- preprocess RPW rows into LDS ----
        #pragma unroll
        for (int r = 0; r < RPW; ++r) {
            int row = row0 + r;
            if (row >= n) {
                *(float2*)(xbase + r * 128 + 2 * lane) = make_float2(0.f, 0.f);
                continue;
            }
            if (PREEXP) {
                const float* src = X + (long)row * 127;
                float u0 = src[2 * lane];
                float u1 = (2 * lane + 1 < 127) ? src[2 * lane + 1] : 0.f;
                float ss = waveReduceSum(u0 * u0 + u1 * u1);
                float nrm = fmaxf(sqrtf(ss), EPSV);
                float ex = expf(nrm), exn = 1.f / ex;
                float ch = 0.5f * (ex + exn);
                float coef = (0.5f * (ex - exn)) / nrm;
                if (lane == 0) xbase[r * 128] = ch;
                xbase[r * 128 + 1 + 2 * lane] = coef * u0;
                if (2 * lane + 1 < 127) xbase[r * 128 + 2 + 2 * lane] = coef * u1;
            } else {
                float2 e = *(const float2*)(X + (long)row * 128 + 2 * lane);
                float t0 = __shfl(e.x, 0, 64);
                float ss = waveReduceSum(e.x * e.x + e.y * e.y);
                float neg_inner = 2.f * t0 * t0 - ss;
                float inv = 1.f / sqrtf(fmaxf(fabsf(neg_inner), EPSV));
                e.x = fmaxf(e.x * inv, 0.f);
                e.y = fmaxf(e.y * inv, 0.f);
                *(float2*)(xbase + r * 128 + 2 * lane) = e;
            }
        }
        // xrow wave-private: within-wave lgkmcnt ordering, no barrier needed
        // ---- GEMM: 8 rows x 2 cols/lane; W coalesced from global (L1/L2) ----
        float2 acc[RPW];
        #pragma unroll
        for (int r = 0; r < RPW; ++r) acc[r] = make_float2(0.f, 0.f);
        #pragma unroll 4
        for (int k0 = 0; k0 < 128; k0 += 4) {
            float2 w0 = *(const float2*)(wcol + (k0 + 0) * 128);
            float2 w1 = *(const float2*)(wcol + (k0 + 1) * 128);
            float2 w2 = *(const float2*)(wcol + (k0 + 2) * 128);
            float2 w3 = *(const float2*)(wcol + (k0 + 3) * 128);
            #pragma unroll
            for (int r = 0; r < RPW; ++r) {
                float4 xq = *(const float4*)(xbase + r * 128 + k0);  // LDS broadcast
                acc[r].x = fmaf(xq.x, w0.x, acc[r].x);
                acc[r].y = fmaf(xq.x, w0.y, acc[r].y);
                acc[r].x = fmaf(xq.y, w1.x, acc[r].x);
                acc[r].y = fmaf(xq.y, w1.y, acc[r].y);
                acc[r].x = fmaf(xq.z, w2.x, acc[r].x);
                acc[r].y = fmaf(xq.z, w2.y, acc[r].y);
                acc[r].x = fmaf(xq.w, w3.x, acc[r].x);
                acc[r].y = fmaf(xq.w, w3.y, acc[r].y);
            }
        }
        // ---- lorentz epilogue per row ----
        #pragma unroll
        for (int r = 0; r < RPW; ++r) {
            int row = row0 + r;
            float ax = acc[r].x + bv.x;
            float ay = acc[r].y + bv.y;
            float t0 = __shfl(ax, 0, 64);
            float ssq = waveReduceSum(ax * ax + ay * ay);
            float timev = sval / (1.f + expf(-t0)) + 1.5f;
            float sq = fmaxf(ssq - t0 * t0, EPSV);
            float fac = sqrtf(fmaxf((timev * timev - 1.f) / sq, EPSV));
            if (row < n) {
                float2 o;
                o.x = (lane == 0) ? timev : ax * fac;
                o.y = ay * fac;
                *(float2*)(out + (long)row * 128 + 2 * lane) = o;
            }
        }
    }
}

// ---------------- CSR gather (agg) ----------------

__global__ void gather_kernel(const float* __restrict__ X, const int* __restrict__ rs,
                              const int* __restrict__ ecol_s, const float* __restrict__ ew_s,
                              float* __restrict__ S, int n)
{
    int wid = threadIdx.x >> 6, lane = threadIdx.x & 63;
    for (int row = blockIdx.x * 4 + wid; row < n; row += gridDim.x * 4) {
        int beg = rs[row], end = rs[row + 1];
        float2 acc = {0.f, 0.f};
        for (int base = beg; base < end; base += 64) {
            int idx = base + lane;
            int colv = (idx < end) ? ecol_s[idx] : 0;
            float wv = (idx < end) ? ew_s[idx] : 0.f;
            int cnt = min(64, end - base);
            for (int j = 0; j < cnt; ++j) {
                int c = __shfl(colv, j, 64);
                float wj = __shfl(wv, j, 64);
                float2 xv = *(const float2*)(X + (long)c * 128 + 2 * lane);
                acc.x = fmaf(wj, xv.x, acc.x);
                acc.y = fmaf(wj, xv.y, acc.y);
            }
        }
        *(float2*)(S + (long)row * 128 + 2 * lane) = acc;
    }
}

// agg2 + lorentz-normalize + sign-flip + logits, fused
__global__ void gather_logits_kernel(
    const float* __restrict__ X, const int* __restrict__ rs,
    const int* __restrict__ ecol_s, const float* __restrict__ ew_s,
    const float* __restrict__ cls, const float* __restrict__ cbias,
    float* __restrict__ outp, int n)
{
    __shared__ float clsS[NCLS * 129];
    __shared__ float cbS[NCLS];
    __shared__ float xsrow[4][128];
    int tid = threadIdx.x;
    for (int idx = tid; idx < NCLS * 128; idx += 256) {
        int c = idx >> 7, k = idx & 127;
        clsS[c * 129 + k] = cls[idx];
    }
    if (tid < NCLS) cbS[tid] = cbias[tid];
    __syncthreads();
    int wid = tid >> 6, lane = tid & 63;
    float* xs = xsrow[wid];
    for (int row = blockIdx.x * 4 + wid; row < n; row += gridDim.x * 4) {
        int beg = rs[row], end = rs[row + 1];
        float2 acc = {0.f, 0.f};
        for (int base = beg; base < end; base += 64) {
            int idx = base + lane;
            int colv = (idx < end) ? ecol_s[idx] : 0;
            float wv = (idx < end) ? ew_s[idx] : 0.f;
            int cnt = min(64, end - base);
            for (int j = 0; j < cnt; ++j) {
                int c = __shfl(colv, j, 64);
                float wj = __shfl(wv, j, 64);
                float2 xv = *(const float2*)(X + (long)c * 128 + 2 * lane);
                acc.x = fmaf(wj, xv.x, acc.x);
                acc.y = fmaf(wj, xv.y, acc.y);
            }
        }
        float t0 = __shfl(acc.x, 0, 64);
        float ss = waveReduceSum(acc.x * acc.x + acc.y * acc.y);
        float neg_inner = 2.f * t0 * t0 - ss;
        float inv = 1.f / sqrtf(fmaxf(fabsf(neg_inner), EPSV));
        float2 xv;
        xv.x = acc.x * inv;
        xv.y = acc.y * inv;
        if (lane == 0) xv.x = -xv.x;
        xs[2 * lane] = xv.x;
        xs[2 * lane + 1] = xv.y;
        if (lane < NCLS) {
            float dot = 0.f;
            #pragma unroll 8
            for (int k = 0; k < 128; ++k)
                dot = fmaf(xs[k], clsS[lane * 129 + k], dot);
            outp[(long)row * NCLS + lane] = 2.f + 2.f * dot + cbS[lane];
        }
    }
}

// ---------------- launch ----------------

extern "C" void kernel_launch(void* const* d_in, const int* in_sizes, int n_in,
                              void* d_out, int out_size, void* d_ws, size_t ws_size,
                              hipStream_t stream) {
    const float* node_feat = (const float*)d_in[0];
    const float* W1   = (const float*)d_in[1];
    const float* b1   = (const float*)d_in[2];
    const float* s1   = (const float*)d_in[3];
    const float* W2   = (const float*)d_in[4];
    const float* b2   = (const float*)d_in[5];
    const float* s2   = (const float*)d_in[6];
    const float* cls  = (const float*)d_in[7];
    const float* cb   = (const float*)d_in[8];
    const float* ew   = (const float*)d_in[9];
    const int*   erow = (const int*)d_in[10];
    const int*   ecol = (const int*)d_in[11];
    float* outp = (float*)d_out;

    const int n = NN;
    const int E = in_sizes[9];
    const int NBLK = (NN + 255) / 256;   // 196

    float* bufA   = (float*)d_ws;                       // NN*128
    float* bufB   = bufA + (size_t)NN * 128;            // NN*128
    int*   rs     = (int*)(bufB + (size_t)NN * 128);    // NN+1
    int*   pos    = rs + (NN + 1);                      // NN
    int*   bsum   = pos + NN;                           // <=256
    int*   ecol_s = bsum + 256;                         // E
    float* ew_s   = (float*)(ecol_s + E);               // E
    float* wt1    = ew_s + E;                           // 128*128
    float* wt2    = wt1 + 128 * 128;                    // 128*128

    // CSR build + W transposes
    (void)hipMemsetAsync(pos, 0, (size_t)NN * sizeof(int), stream);
    transpose128<<<64, 256, 0, stream>>>(W1, wt1);
    transpose128<<<64, 256, 0, stream>>>(W2, wt2);
    hist_kernel<<<2048, 256, 0, stream>>>(erow, pos, E);
    scan1_kernel<<<NBLK, 256, 0, stream>>>(pos, rs, bsum, n);
    scan2_kernel<<<1, 256, 0, stream>>>(bsum, NBLK);
    scan3_kernel<<<NBLK, 256, 0, stream>>>(rs, bsum, n, E);
    (void)hipMemcpyAsync(pos, rs, (size_t)NN * sizeof(int), hipMemcpyDeviceToDevice, stream);
    fill_kernel<<<2048, 256, 0, stream>>>(erow, ecol, ew, pos, ecol_s, ew_s, E);

    const int nslabs = (n + RPW - 1) / RPW;     // 6250
    const int LGRID = (nslabs + 3) / 4;         // 1563: ~1 slab per wave

    // pipeline
    linear_lorentz<1><<<LGRID, 256, 0, stream>>>(node_feat, wt1, b1, s1, bufA, n);  // expmap+L1
    gather_kernel<<<4096, 256, 0, stream>>>(bufA, rs, ecol_s, ew_s, bufB, n);       // agg1
    linear_lorentz<0><<<LGRID, 256, 0, stream>>>(bufB, wt2, b2, s2, bufA, n);       // norm+relu+L2
    gather_logits_kernel<<<4096, 256, 0, stream>>>(bufA, rs, ecol_s, ew_s, cls, cb, outp, n); // agg2+logits
}

// Round 9
// 360.536 us; speedup vs baseline: 1.1973x; 1.0723x over previous
//
#include <hip/hip_runtime.h>
#include <math.h>

#define NN 50000
#define DD 128
#define NCLS 40
#define EPSV 1e-8f

__device__ __forceinline__ float waveReduceSum(float v) {
    for (int off = 32; off > 0; off >>= 1) v += __shfl_xor(v, off, 64);
    return v;
}

__device__ __forceinline__ float bcastlane0(float v) {
    return __int_as_float(__builtin_amdgcn_readfirstlane(__float_as_int(v)));
}

// ---------------- CSR build ----------------

__global__ void hist_kernel(const int* __restrict__ erow, int* __restrict__ cnt, int E) {
    for (int e = blockIdx.x * blockDim.x + threadIdx.x; e < E; e += gridDim.x * blockDim.x)
        atomicAdd(&cnt[erow[e]], 1);
}

__global__ void scan1_kernel(const int* __restrict__ cnt, int* __restrict__ rs,
                             int* __restrict__ bsum, int n) {
    __shared__ int sdata[256];
    int tid = threadIdx.x;
    int gid = blockIdx.x * 256 + tid;
    int v = (gid < n) ? cnt[gid] : 0;
    sdata[tid] = v;
    __syncthreads();
    for (int off = 1; off < 256; off <<= 1) {
        int t = (tid >= off) ? sdata[tid - off] : 0;
        __syncthreads();
        sdata[tid] += t;
        __syncthreads();
    }
    if (gid < n) rs[gid] = sdata[tid] - v;
    if (tid == 255) bsum[blockIdx.x] = sdata[255];
}

__global__ void scan2_kernel(int* __restrict__ bsum, int nb) {
    __shared__ int sdata[256];
    int tid = threadIdx.x;
    int v = (tid < nb) ? bsum[tid] : 0;
    sdata[tid] = v;
    __syncthreads();
    for (int off = 1; off < 256; off <<= 1) {
        int t = (tid >= off) ? sdata[tid - off] : 0;
        __syncthreads();
        sdata[tid] += t;
        __syncthreads();
    }
    if (tid < nb) bsum[tid] = sdata[tid] - v;
}

__global__ void scan3_kernel(int* __restrict__ rs, const int* __restrict__ bsum, int n, int E) {
    int gid = blockIdx.x * 256 + threadIdx.x;
    if (gid < n) rs[gid] += bsum[blockIdx.x];
    else if (gid == n) rs[n] = E;
}

__global__ void fill_kernel(const int* __restrict__ erow, const int* __restrict__ ecol,
                            const float* __restrict__ ew, int* __restrict__ pos,
                            int* __restrict__ ecol_s, float* __restrict__ ew_s, int E) {
    for (int e = blockIdx.x * blockDim.x + threadIdx.x; e < E; e += gridDim.x * blockDim.x) {
        int r = erow[e];
        int p = atomicAdd(&pos[r], 1);
        ecol_s[p] = ecol[e];
        ew_s[p] = ew[e];
    }
}

// ---------------- W transpose (once per launch) ----------------
__global__ void transpose128(const float* __restrict__ W, float* __restrict__ Wt) {
    int idx = blockIdx.x * 256 + threadIdx.x;
    if (idx < 128 * 128) {
        int i = idx >> 7, k = idx & 127;
        Wt[k * 128 + i] = W[idx];
    }
}

// ---------------- fused linears (unchanged from round 8) ----------------
#define RPW 8
template <int PREEXP>
__global__ __launch_bounds__(256, 8) void linear_lorentz(
    const float* __restrict__ X, const float* __restrict__ Wt,
    const float* __restrict__ bias, const float* __restrict__ logs,
    float* __restrict__ out, int n)
{
    __shared__ float xrow[4][RPW * 128];
    int tid = threadIdx.x;
    int wid = tid >> 6, lane = tid & 63;
    float2 bv = *(const float2*)(bias + 2 * lane);
    float sval = fminf(expf(logs[0]), 10.f);
    float* xbase = xrow[wid];
    const float* wcol = Wt + 2 * lane;
    int nslabs = (n + RPW - 1) / RPW;
    for (int slab = blockIdx.x * 4 + wid; slab < nslabs; slab += gridDim.x * 4) {
        int row0 = slab * RPW;
        #pragma unroll
        for (int r = 0; r < RPW; ++r) {
            int row = row0 + r;
            if (row >= n) {
                *(float2*)(xbase + r * 128 + 2 * lane) = make_float2(0.f, 0.f);
                continue;
            }
            if (PREEXP) {
                const float* src = X + (long)row * 127;
                float u0 = src[2 * lane];
                float u1 = (2 * lane + 1 < 127) ? src[2 * lane + 1] : 0.f;
                float ss = waveReduceSum(u0 * u0 + u1 * u1);
                float nrm = fmaxf(sqrtf(ss), EPSV);
                float ex = expf(nrm), exn = 1.f / ex;
                float ch = 0.5f * (ex + exn);
                float coef = (0.5f * (ex - exn)) / nrm;
                if (lane == 0) xbase[r * 128] = ch;
                xbase[r * 128 + 1 + 2 * lane] = coef * u0;
                if (2 * lane + 1 < 127) xbase[r * 128 + 2 + 2 * lane] = coef * u1;
            } else {
                float2 e = *(const float2*)(X + (long)row * 128 + 2 * lane);
                float t0 = __shfl(e.x, 0, 64);
                float ss = waveReduceSum(e.x * e.x + e.y * e.y);
                float neg_inner = 2.f * t0 * t0 - ss;
                float inv = 1.f / sqrtf(fmaxf(fabsf(neg_inner), EPSV));
                e.x = fmaxf(e.x * inv, 0.f);
                e.y = fmaxf(e.y * inv, 0.f);
                *(float2*)(xbase + r * 128 + 2 * lane) = e;
            }
        }
        float2 acc[RPW];
        #pragma unroll
        for (int r = 0; r < RPW; ++r) acc[r] = make_float2(0.f, 0.f);
        #pragma unroll 4
        for (int k0 = 0; k0 < 128; k0 += 4) {
            float2 w0 = *(const float2*)(wcol + (k0 + 0) * 128);
            float2 w1 = *(const float2*)(wcol + (k0 + 1) * 128);
            float2 w2 = *(const float2*)(wcol + (k0 + 2) * 128);
            float2 w3 = *(const float2*)(wcol + (k0 + 3) * 128);
            #pragma unroll
            for (int r = 0; r < RPW; ++r) {
                float4 xq = *(const float4*)(xbase + r * 128 + k0);
                acc[r].x = fmaf(xq.x, w0.x, acc[r].x);
                acc[r].y = fmaf(xq.x, w0.y, acc[r].y);
                acc[r].x = fmaf(xq.y, w1.x, acc[r].x);
                acc[r].y = fmaf(xq.y, w1.y, acc[r].y);
                acc[r].x = fmaf(xq.z, w2.x, acc[r].x);
                acc[r].y = fmaf(xq.z, w2.y, acc[r].y);
                acc[r].x = fmaf(xq.w, w3.x, acc[r].x);
                acc[r].y = fmaf(xq.w, w3.y, acc[r].y);
            }
        }
        #pragma unroll
        for (int r = 0; r < RPW; ++r) {
            int row = row0 + r;
            float ax = acc[r].x + bv.x;
            float ay = acc[r].y + bv.y;
            float t0 = __shfl(ax, 0, 64);
            float ssq = waveReduceSum(ax * ax + ay * ay);
            float timev = sval / (1.f + expf(-t0)) + 1.5f;
            float sq = fmaxf(ssq - t0 * t0, EPSV);
            float fac = sqrtf(fmaxf((timev * timev - 1.f) / sq, EPSV));
            if (row < n) {
                float2 o;
                o.x = (lane == 0) ? timev : ax * fac;
                o.y = ay * fac;
                *(float2*)(out + (long)row * 128 + 2 * lane) = o;
            }
        }
    }
}

// ---------------- CSR gather, 4 edge-groups of 16 lanes ----------------
// Group g handles edges beg+g, beg+g+4, ... Each group reads its edge's
// X row as 16 lanes x 2 float4 (512B coalesced); col/weight loaded
// uniform-address per group (L1 broadcast). 4 rows in flight per wave.

__global__ __launch_bounds__(256, 8) void gather_kernel(
    const float* __restrict__ X, const int* __restrict__ rs,
    const int* __restrict__ ecol_s, const float* __restrict__ ew_s,
    float* __restrict__ S, int n)
{
    int wid = threadIdx.x >> 6, lane = threadIdx.x & 63;
    int g = lane >> 4, l16 = lane & 15;
    for (int row = blockIdx.x * 4 + wid; row < n; row += gridDim.x * 4) {
        int beg = rs[row], end = rs[row + 1];
        float a0=0.f,a1=0.f,a2=0.f,a3=0.f,a4=0.f,a5=0.f,a6=0.f,a7=0.f;
        for (int idx = beg + g; idx < end; idx += 4) {
            int c = ecol_s[idx];
            float w = ew_s[idx];
            const float* xp = X + (long)c * 128 + l16 * 8;
            float4 xa = *(const float4*)xp;
            float4 xb = *(const float4*)(xp + 4);
            a0 = fmaf(w, xa.x, a0); a1 = fmaf(w, xa.y, a1);
            a2 = fmaf(w, xa.z, a2); a3 = fmaf(w, xa.w, a3);
            a4 = fmaf(w, xb.x, a4); a5 = fmaf(w, xb.y, a5);
            a6 = fmaf(w, xb.z, a6); a7 = fmaf(w, xb.w, a7);
        }
        // cross-group reduce (xor 16, 32): all groups end with totals
        a0 += __shfl_xor(a0, 16, 64); a0 += __shfl_xor(a0, 32, 64);
        a1 += __shfl_xor(a1, 16, 64); a1 += __shfl_xor(a1, 32, 64);
        a2 += __shfl_xor(a2, 16, 64); a2 += __shfl_xor(a2, 32, 64);
        a3 += __shfl_xor(a3, 16, 64); a3 += __shfl_xor(a3, 32, 64);
        a4 += __shfl_xor(a4, 16, 64); a4 += __shfl_xor(a4, 32, 64);
        a5 += __shfl_xor(a5, 16, 64); a5 += __shfl_xor(a5, 32, 64);
        a6 += __shfl_xor(a6, 16, 64); a6 += __shfl_xor(a6, 32, 64);
        a7 += __shfl_xor(a7, 16, 64); a7 += __shfl_xor(a7, 32, 64);
        if (g == 0) {
            float* sp = S + (long)row * 128 + l16 * 8;
            *(float4*)sp       = make_float4(a0, a1, a2, a3);
            *(float4*)(sp + 4) = make_float4(a4, a5, a6, a7);
        }
    }
}

// agg2 + lorentz-normalize + sign-flip + logits, fused (grouped gather)
__global__ __launch_bounds__(256, 8) void gather_logits_kernel(
    const float* __restrict__ X, const int* __restrict__ rs,
    const int* __restrict__ ecol_s, const float* __restrict__ ew_s,
    const float* __restrict__ cls, const float* __restrict__ cbias,
    float* __restrict__ outp, int n)
{
    __shared__ float clsS[NCLS * 129];
    __shared__ float cbS[NCLS];
    __shared__ float xsrow[4][128];
    int tid = threadIdx.x;
    for (int idx = tid; idx < NCLS * 128; idx += 256) {
        int c = idx >> 7, k = idx & 127;
        clsS[c * 129 + k] = cls[idx];
    }
    if (tid < NCLS) cbS[tid] = cbias[tid];
    __syncthreads();
    int wid = tid >> 6, lane = tid & 63;
    int g = lane >> 4, l16 = lane & 15;
    float* xs = xsrow[wid];
    for (int row = blockIdx.x * 4 + wid; row < n; row += gridDim.x * 4) {
        int beg = rs[row], end = rs[row + 1];
        float a0=0.f,a1=0.f,a2=0.f,a3=0.f,a4=0.f,a5=0.f,a6=0.f,a7=0.f;
        for (int idx = beg + g; idx < end; idx += 4) {
            int c = ecol_s[idx];
            float w = ew_s[idx];
            const float* xp = X + (long)c * 128 + l16 * 8;
            float4 xa = *(const float4*)xp;
            float4 xb = *(const float4*)(xp + 4);
            a0 = fmaf(w, xa.x, a0); a1 = fmaf(w, xa.y, a1);
            a2 = fmaf(w, xa.z, a2); a3 = fmaf(w, xa.w, a3);
            a4 = fmaf(w, xb.x, a4); a5 = fmaf(w, xb.y, a5);
            a6 = fmaf(w, xb.z, a6); a7 = fmaf(w, xb.w, a7);
        }
        a0 += __shfl_xor(a0, 16, 64); a0 += __shfl_xor(a0, 32, 64);
        a1 += __shfl_xor(a1, 16, 64); a1 += __shfl_xor(a1, 32, 64);
        a2 += __shfl_xor(a2, 16, 64); a2 += __shfl_xor(a2, 32, 64);
        a3 += __shfl_xor(a3, 16, 64); a3 += __shfl_xor(a3, 32, 64);
        a4 += __shfl_xor(a4, 16, 64); a4 += __shfl_xor(a4, 32, 64);
        a5 += __shfl_xor(a5, 16, 64); a5 += __shfl_xor(a5, 32, 64);
        a6 += __shfl_xor(a6, 16, 64); a6 += __shfl_xor(a6, 32, 64);
        a7 += __shfl_xor(a7, 16, 64); a7 += __shfl_xor(a7, 32, 64);
        // normalize in grouped layout: ss = sum of squares over all 128 cols
        float ss = a0*a0 + a1*a1 + a2*a2 + a3*a3 + a4*a4 + a5*a5 + a6*a6 + a7*a7;
        ss += __shfl_xor(ss, 1, 64);
        ss += __shfl_xor(ss, 2, 64);
        ss += __shfl_xor(ss, 4, 64);
        ss += __shfl_xor(ss, 8, 64);
        float t0 = bcastlane0(a0);                  // col 0 (lane 0 holds it)
        float neg_inner = 2.f * t0 * t0 - ss;
        float inv = 1.f / sqrtf(fmaxf(fabsf(neg_inner), EPSV));
        if (g == 0) {
            float v0 = a0 * inv;
            if (l16 == 0) v0 = -v0;                 // sign-flip time coord
            float* xp = xs + l16 * 8;
            *(float4*)xp       = make_float4(v0, a1 * inv, a2 * inv, a3 * inv);
            *(float4*)(xp + 4) = make_float4(a4 * inv, a5 * inv, a6 * inv, a7 * inv);
        }
        // wave-private LDS: within-wave ordering, no barrier
        if (lane < NCLS) {
            float dot = 0.f;
            #pragma unroll 8
            for (int k = 0; k < 128; ++k)
                dot = fmaf(xs[k], clsS[lane * 129 + k], dot);
            outp[(long)row * NCLS + lane] = 2.f + 2.f * dot + cbS[lane];
        }
    }
}

// ---------------- launch ----------------

extern "C" void kernel_launch(void* const* d_in, const int* in_sizes, int n_in,
                              void* d_out, int out_size, void* d_ws, size_t ws_size,
                              hipStream_t stream) {
    const float* node_feat = (const float*)d_in[0];
    const float* W1   = (const float*)d_in[1];
    const float* b1   = (const float*)d_in[2];
    const float* s1   = (const float*)d_in[3];
    const float* W2   = (const float*)d_in[4];
    const float* b2   = (const float*)d_in[5];
    const float* s2   = (const float*)d_in[6];
    const float* cls  = (const float*)d_in[7];
    const float* cb   = (const float*)d_in[8];
    const float* ew   = (const float*)d_in[9];
    const int*   erow = (const int*)d_in[10];
    const int*   ecol = (const int*)d_in[11];
    float* outp = (float*)d_out;

    const int n = NN;
    const int E = in_sizes[9];
    const int NBLK = (NN + 255) / 256;   // 196

    float* bufA   = (float*)d_ws;                       // NN*128
    float* bufB   = bufA + (size_t)NN * 128;            // NN*128
    int*   rs     = (int*)(bufB + (size_t)NN * 128);    // NN+1
    int*   pos    = rs + (NN + 1);                      // NN
    int*   bsum   = pos + NN;                           // <=256
    int*   ecol_s = bsum + 256;                         // E
    float* ew_s   = (float*)(ecol_s + E);               // E
    float* wt1    = ew_s + E;                           // 128*128
    float* wt2    = wt1 + 128 * 128;                    // 128*128

    // CSR build + W transposes
    (void)hipMemsetAsync(pos, 0, (size_t)NN * sizeof(int), stream);
    transpose128<<<64, 256, 0, stream>>>(W1, wt1);
    transpose128<<<64, 256, 0, stream>>>(W2, wt2);
    hist_kernel<<<2048, 256, 0, stream>>>(erow, pos, E);
    scan1_kernel<<<NBLK, 256, 0, stream>>>(pos, rs, bsum, n);
    scan2_kernel<<<1, 256, 0, stream>>>(bsum, NBLK);
    scan3_kernel<<<NBLK, 256, 0, stream>>>(rs, bsum, n, E);
    (void)hipMemcpyAsync(pos, rs, (size_t)NN * sizeof(int), hipMemcpyDeviceToDevice, stream);
    fill_kernel<<<2048, 256, 0, stream>>>(erow, ecol, ew, pos, ecol_s, ew_s, E);

    const int nslabs = (n + RPW - 1) / RPW;     // 6250
    const int LGRID = (nslabs + 3) / 4;         // 1563
    const int GGRID = (n + 3) / 4;              // 12500

    // pipeline
    linear_lorentz<1><<<LGRID, 256, 0, stream>>>(node_feat, wt1, b1, s1, bufA, n);  // expmap+L1
    gather_kernel<<<GGRID, 256, 0, stream>>>(bufA, rs, ecol_s, ew_s, bufB, n);      // agg1
    linear_lorentz<0><<<LGRID, 256, 0, stream>>>(bufB, wt2, b2, s2, bufA, n);       // norm+relu+L2
    gather_logits_kernel<<<GGRID, 256, 0, stream>>>(bufA, rs, ecol_s, ew_s, cls, cb, outp, n); // agg2+logits
}

// Round 10
// 323.088 us; speedup vs baseline: 1.3361x; 1.1159x over previous
//
#include <hip/hip_runtime.h>
#include <hip/hip_fp16.h>
#include <math.h>

#define NN 50000
#define DD 128
#define NCLS 40
#define EPSV 1e-8f

__device__ __forceinline__ float waveReduceSum(float v) {
    for (int off = 32; off > 0; off >>= 1) v += __shfl_xor(v, off, 64);
    return v;
}

__device__ __forceinline__ float bcastlane0(float v) {
    return __int_as_float(__builtin_amdgcn_readfirstlane(__float_as_int(v)));
}

__device__ __forceinline__ float h_lo(unsigned int w) {
    return __half2float(__ushort_as_half((unsigned short)(w & 0xffffu)));
}
__device__ __forceinline__ float h_hi(unsigned int w) {
    return __half2float(__ushort_as_half((unsigned short)(w >> 16)));
}
__device__ __forceinline__ unsigned int h_pack(float a, float b) {
    return (unsigned int)__half_as_ushort(__float2half(a)) |
           ((unsigned int)__half_as_ushort(__float2half(b)) << 16);
}

// ---------------- CSR build ----------------

__global__ void hist_kernel(const int* __restrict__ erow, int* __restrict__ cnt, int E) {
    for (int e = blockIdx.x * blockDim.x + threadIdx.x; e < E; e += gridDim.x * blockDim.x)
        atomicAdd(&cnt[erow[e]], 1);
}

__global__ void scan1_kernel(const int* __restrict__ cnt, int* __restrict__ rs,
                             int* __restrict__ bsum, int n) {
    __shared__ int sdata[256];
    int tid = threadIdx.x;
    int gid = blockIdx.x * 256 + tid;
    int v = (gid < n) ? cnt[gid] : 0;
    sdata[tid] = v;
    __syncthreads();
    for (int off = 1; off < 256; off <<= 1) {
        int t = (tid >= off) ? sdata[tid - off] : 0;
        __syncthreads();
        sdata[tid] += t;
        __syncthreads();
    }
    if (gid < n) rs[gid] = sdata[tid] - v;
    if (tid == 255) bsum[blockIdx.x] = sdata[255];
}

__global__ void scan2_kernel(int* __restrict__ bsum, int nb) {
    __shared__ int sdata[256];
    int tid = threadIdx.x;
    int v = (tid < nb) ? bsum[tid] : 0;
    sdata[tid] = v;
    __syncthreads();
    for (int off = 1; off < 256; off <<= 1) {
        int t = (tid >= off) ? sdata[tid - off] : 0;
        __syncthreads();
        sdata[tid] += t;
        __syncthreads();
    }
    if (tid < nb) bsum[tid] = sdata[tid] - v;
}

__global__ void scan3_kernel(int* __restrict__ rs, const int* __restrict__ bsum, int n, int E) {
    int gid = blockIdx.x * 256 + threadIdx.x;
    if (gid < n) rs[gid] += bsum[blockIdx.x];
    else if (gid == n) rs[n] = E;
}

__global__ void fill_kernel(const int* __restrict__ erow, const int* __restrict__ ecol,
                            const float* __restrict__ ew, int* __restrict__ pos,
                            int* __restrict__ ecol_s, float* __restrict__ ew_s, int E) {
    for (int e = blockIdx.x * blockDim.x + threadIdx.x; e < E; e += gridDim.x * blockDim.x) {
        int r = erow[e];
        int p = atomicAdd(&pos[r], 1);
        ecol_s[p] = ecol[e];
        ew_s[p] = ew[e];
    }
}

// ---------------- W transpose (once per launch) ----------------
__global__ void transpose128(const float* __restrict__ W, float* __restrict__ Wt) {
    int idx = blockIdx.x * 256 + threadIdx.x;
    if (idx < 128 * 128) {
        int i = idx >> 7, k = idx & 127;
        Wt[k * 128 + i] = W[idx];
    }
}

// ---------------- fused linears ----------------
// 8 rows/wave; x slab in LDS (uniform b128 broadcast); W pre-transposed in
// global, coalesced + L1/L2-hot. Output written as PACKED FP16 (uint/lane):
// halves the gather kernels' X traffic.
// PREEXP=1: X=node_feat (N,127), expmap0 first. PREEXP=0: X=(N,128) fp32 agg
// sums, lorentz-normalize + relu first.
#define RPW 8
template <int PREEXP>
__global__ __launch_bounds__(256, 8) void linear_lorentz(
    const float* __restrict__ X, const float* __restrict__ Wt,
    const float* __restrict__ bias, const float* __restrict__ logs,
    unsigned int* __restrict__ outh, int n)
{
    __shared__ float xrow[4][RPW * 128];
    int tid = threadIdx.x;
    int wid = tid >> 6, lane = tid & 63;
    float2 bv = *(const float2*)(bias + 2 * lane);
    float sval = fminf(expf(logs[0]), 10.f);
    float* xbase = xrow[wid];
    const float* wcol = Wt + 2 * lane;
    int nslabs = (n + RPW - 1) / RPW;
    for (int slab = blockIdx.x * 4 + wid; slab < nslabs; slab += gridDim.x * 4) {
        int row0 = slab * RPW;
        #pragma unroll
        for (int r = 0; r < RPW; ++r) {
            int row = row0 + r;
            if (row >= n) {
                *(float2*)(xbase + r * 128 + 2 * lane) = make_float2(0.f, 0.f);
                continue;
            }
            if (PREEXP) {
                const float* src = X + (long)row * 127;
                float u0 = src[2 * lane];
                float u1 = (2 * lane + 1 < 127) ? src[2 * lane + 1] : 0.f;
                float ss = waveReduceSum(u0 * u0 + u1 * u1);
                float nrm = fmaxf(sqrtf(ss), EPSV);
                float ex = expf(nrm), exn = 1.f / ex;
                float ch = 0.5f * (ex + exn);
                float coef = (0.5f * (ex - exn)) / nrm;
                if (lane == 0) xbase[r * 128] = ch;
                xbase[r * 128 + 1 + 2 * lane] = coef * u0;
                if (2 * lane + 1 < 127) xbase[r * 128 + 2 + 2 * lane] = coef * u1;
            } else {
                float2 e = *(const float2*)(X + (long)row * 128 + 2 * lane);
                float t0 = __shfl(e.x, 0, 64);
                float ss = waveReduceSum(e.x * e.x + e.y * e.y);
                float neg_inner = 2.f * t0 * t0 - ss;
                float inv = 1.f / sqrtf(fmaxf(fabsf(neg_inner), EPSV));
                e.x = fmaxf(e.x * inv, 0.f);
                e.y = fmaxf(e.y * inv, 0.f);
                *(float2*)(xbase + r * 128 + 2 * lane) = e;
            }
        }
        float2 acc[RPW];
        #pragma unroll
        for (int r = 0; r < RPW; ++r) acc[r] = make_float2(0.f, 0.f);
        #pragma unroll 4
        for (int k0 = 0; k0 < 128; k0 += 4) {
            float2 w0 = *(const float2*)(wcol + (k0 + 0) * 128);
            float2 w1 = *(const float2*)(wcol + (k0 + 1) * 128);
            float2 w2 = *(const float2*)(wcol + (k0 + 2) * 128);
            float2 w3 = *(const float2*)(wcol + (k0 + 3) * 128);
            #pragma unroll
            for (int r = 0; r < RPW; ++r) {
                float4 xq = *(const float4*)(xbase + r * 128 + k0);
                acc[r].x = fmaf(xq.x, w0.x, acc[r].x);
                acc[r].y = fmaf(xq.x, w0.y, acc[r].y);
                acc[r].x = fmaf(xq.y, w1.x, acc[r].x);
                acc[r].y = fmaf(xq.y, w1.y, acc[r].y);
                acc[r].x = fmaf(xq.z, w2.x, acc[r].x);
                acc[r].y = fmaf(xq.z, w2.y, acc[r].y);
                acc[r].x = fmaf(xq.w, w3.x, acc[r].x);
                acc[r].y = fmaf(xq.w, w3.y, acc[r].y);
            }
        }
        #pragma unroll
        for (int r = 0; r < RPW; ++r) {
            int row = row0 + r;
            float ax = acc[r].x + bv.x;
            float ay = acc[r].y + bv.y;
            float t0 = __shfl(ax, 0, 64);
            float ssq = waveReduceSum(ax * ax + ay * ay);
            float timev = sval / (1.f + expf(-t0)) + 1.5f;
            float sq = fmaxf(ssq - t0 * t0, EPSV);
            float fac = sqrtf(fmaxf((timev * timev - 1.f) / sq, EPSV));
            if (row < n) {
                float o0 = (lane == 0) ? timev : ax * fac;
                float o1 = ay * fac;
                outh[(long)row * 64 + lane] = h_pack(o0, o1);  // cols 2l,2l+1
            }
        }
    }
}

// ---------------- CSR gather, 4 edge-groups of 16 lanes, FP16 X ----------------
// Row = 64 uints (128 fp16). Group reads 16 lanes x 1 dwordx4 = full row.

__global__ __launch_bounds__(256, 8) void gather_kernel(
    const unsigned int* __restrict__ Xh, const int* __restrict__ rs,
    const int* __restrict__ ecol_s, const float* __restrict__ ew_s,
    float* __restrict__ S, int n)
{
    int wid = threadIdx.x >> 6, lane = threadIdx.x & 63;
    int g = lane >> 4, l16 = lane & 15;
    for (int row = blockIdx.x * 4 + wid; row < n; row += gridDim.x * 4) {
        int beg = rs[row], end = rs[row + 1];
        float a0=0.f,a1=0.f,a2=0.f,a3=0.f,a4=0.f,a5=0.f,a6=0.f,a7=0.f;
        #pragma unroll 2
        for (int idx = beg + g; idx < end; idx += 4) {
            int c = ecol_s[idx];
            float w = ew_s[idx];
            uint4 xw = *(const uint4*)(Xh + (long)c * 64 + l16 * 4);
            a0 = fmaf(w, h_lo(xw.x), a0); a1 = fmaf(w, h_hi(xw.x), a1);
            a2 = fmaf(w, h_lo(xw.y), a2); a3 = fmaf(w, h_hi(xw.y), a3);
            a4 = fmaf(w, h_lo(xw.z), a4); a5 = fmaf(w, h_hi(xw.z), a5);
            a6 = fmaf(w, h_lo(xw.w), a6); a7 = fmaf(w, h_hi(xw.w), a7);
        }
        a0 += __shfl_xor(a0, 16, 64); a0 += __shfl_xor(a0, 32, 64);
        a1 += __shfl_xor(a1, 16, 64); a1 += __shfl_xor(a1, 32, 64);
        a2 += __shfl_xor(a2, 16, 64); a2 += __shfl_xor(a2, 32, 64);
        a3 += __shfl_xor(a3, 16, 64); a3 += __shfl_xor(a3, 32, 64);
        a4 += __shfl_xor(a4, 16, 64); a4 += __shfl_xor(a4, 32, 64);
        a5 += __shfl_xor(a5, 16, 64); a5 += __shfl_xor(a5, 32, 64);
        a6 += __shfl_xor(a6, 16, 64); a6 += __shfl_xor(a6, 32, 64);
        a7 += __shfl_xor(a7, 16, 64); a7 += __shfl_xor(a7, 32, 64);
        if (g == 0) {
            float* sp = S + (long)row * 128 + l16 * 8;
            *(float4*)sp       = make_float4(a0, a1, a2, a3);
            *(float4*)(sp + 4) = make_float4(a4, a5, a6, a7);
        }
    }
}

// agg2 + lorentz-normalize + sign-flip + logits, fused (grouped, FP16 X)
__global__ __launch_bounds__(256, 8) void gather_logits_kernel(
    const unsigned int* __restrict__ Xh, const int* __restrict__ rs,
    const int* __restrict__ ecol_s, const float* __restrict__ ew_s,
    const float* __restrict__ cls, const float* __restrict__ cbias,
    float* __restrict__ outp, int n)
{
    __shared__ float clsS[NCLS * 129];
    __shared__ float cbS[NCLS];
    __shared__ float xsrow[4][128];
    int tid = threadIdx.x;
    for (int idx = tid; idx < NCLS * 128; idx += 256) {
        int c = idx >> 7, k = idx & 127;
        clsS[c * 129 + k] = cls[idx];
    }
    if (tid < NCLS) cbS[tid] = cbias[tid];
    __syncthreads();
    int wid = tid >> 6, lane = tid & 63;
    int g = lane >> 4, l16 = lane & 15;
    float* xs = xsrow[wid];
    for (int row = blockIdx.x * 4 + wid; row < n; row += gridDim.x * 4) {
        int beg = rs[row], end = rs[row + 1];
        float a0=0.f,a1=0.f,a2=0.f,a3=0.f,a4=0.f,a5=0.f,a6=0.f,a7=0.f;
        #pragma unroll 2
        for (int idx = beg + g; idx < end; idx += 4) {
            int c = ecol_s[idx];
            float w = ew_s[idx];
            uint4 xw = *(const uint4*)(Xh + (long)c * 64 + l16 * 4);
            a0 = fmaf(w, h_lo(xw.x), a0); a1 = fmaf(w, h_hi(xw.x), a1);
            a2 = fmaf(w, h_lo(xw.y), a2); a3 = fmaf(w, h_hi(xw.y), a3);
            a4 = fmaf(w, h_lo(xw.z), a4); a5 = fmaf(w, h_hi(xw.z), a5);
            a6 = fmaf(w, h_lo(xw.w), a6); a7 = fmaf(w, h_hi(xw.w), a7);
        }
        a0 += __shfl_xor(a0, 16, 64); a0 += __shfl_xor(a0, 32, 64);
        a1 += __shfl_xor(a1, 16, 64); a1 += __shfl_xor(a1, 32, 64);
        a2 += __shfl_xor(a2, 16, 64); a2 += __shfl_xor(a2, 32, 64);
        a3 += __shfl_xor(a3, 16, 64); a3 += __shfl_xor(a3, 32, 64);
        a4 += __shfl_xor(a4, 16, 64); a4 += __shfl_xor(a4, 32, 64);
        a5 += __shfl_xor(a5, 16, 64); a5 += __shfl_xor(a5, 32, 64);
        a6 += __shfl_xor(a6, 16, 64); a6 += __shfl_xor(a6, 32, 64);
        a7 += __shfl_xor(a7, 16, 64); a7 += __shfl_xor(a7, 32, 64);
        float ss = a0*a0 + a1*a1 + a2*a2 + a3*a3 + a4*a4 + a5*a5 + a6*a6 + a7*a7;
        ss += __shfl_xor(ss, 1, 64);
        ss += __shfl_xor(ss, 2, 64);
        ss += __shfl_xor(ss, 4, 64);
        ss += __shfl_xor(ss, 8, 64);
        float t0 = bcastlane0(a0);
        float neg_inner = 2.f * t0 * t0 - ss;
        float inv = 1.f / sqrtf(fmaxf(fabsf(neg_inner), EPSV));
        if (g == 0) {
            float v0 = a0 * inv;
            if (l16 == 0) v0 = -v0;
            float* xp = xs + l16 * 8;
            *(float4*)xp       = make_float4(v0, a1 * inv, a2 * inv, a3 * inv);
            *(float4*)(xp + 4) = make_float4(a4 * inv, a5 * inv, a6 * inv, a7 * inv);
        }
        if (lane < NCLS) {
            float dot = 0.f;
            #pragma unroll 8
            for (int k = 0; k < 128; ++k)
                dot = fmaf(xs[k], clsS[lane * 129 + k], dot);
            outp[(long)row * NCLS + lane] = 2.f + 2.f * dot + cbS[lane];
        }
    }
}

// ---------------- launch ----------------

extern "C" void kernel_launch(void* const* d_in, const int* in_sizes, int n_in,
                              void* d_out, int out_size, void* d_ws, size_t ws_size,
                              hipStream_t stream) {
    const float* node_feat = (const float*)d_in[0];
    const float* W1   = (const float*)d_in[1];
    const float* b1   = (const float*)d_in[2];
    const float* s1   = (const float*)d_in[3];
    const float* W2   = (const float*)d_in[4];
    const float* b2   = (const float*)d_in[5];
    const float* s2   = (const float*)d_in[6];
    const float* cls  = (const float*)d_in[7];
    const float* cb   = (const float*)d_in[8];
    const float* ew   = (const float*)d_in[9];
    const int*   erow = (const int*)d_in[10];
    const int*   ecol = (const int*)d_in[11];
    float* outp = (float*)d_out;

    const int n = NN;
    const int E = in_sizes[9];
    const int NBLK = (NN + 255) / 256;   // 196

    float*        bufB  = (float*)d_ws;                     // NN*128 fp32 (agg1 out)
    unsigned int* bufH  = (unsigned int*)(bufB + (size_t)NN * 128);  // NN*64 uint (fp16 X)
    int*   rs     = (int*)(bufH + (size_t)NN * 64);         // NN+1
    int*   pos    = rs + (NN + 1);                          // NN
    int*   bsum   = pos + NN;                               // <=256
    int*   ecol_s = bsum + 256;                             // E
    float* ew_s   = (float*)(ecol_s + E);                   // E
    float* wt1    = ew_s + E;                               // 128*128
    float* wt2    = wt1 + 128 * 128;                        // 128*128

    // CSR build + W transposes
    (void)hipMemsetAsync(pos, 0, (size_t)NN * sizeof(int), stream);
    transpose128<<<64, 256, 0, stream>>>(W1, wt1);
    transpose128<<<64, 256, 0, stream>>>(W2, wt2);
    hist_kernel<<<2048, 256, 0, stream>>>(erow, pos, E);
    scan1_kernel<<<NBLK, 256, 0, stream>>>(pos, rs, bsum, n);
    scan2_kernel<<<1, 256, 0, stream>>>(bsum, NBLK);
    scan3_kernel<<<NBLK, 256, 0, stream>>>(rs, bsum, n, E);
    (void)hipMemcpyAsync(pos, rs, (size_t)NN * sizeof(int), hipMemcpyDeviceToDevice, stream);
    fill_kernel<<<2048, 256, 0, stream>>>(erow, ecol, ew, pos, ecol_s, ew_s, E);

    const int nslabs = (n + RPW - 1) / RPW;     // 6250
    const int LGRID = (nslabs + 3) / 4;         // 1563
    const int GGRID = (n + 3) / 4;              // 12500

    // pipeline
    linear_lorentz<1><<<LGRID, 256, 0, stream>>>(node_feat, wt1, b1, s1, bufH, n);  // expmap+L1 -> fp16
    gather_kernel<<<GGRID, 256, 0, stream>>>(bufH, rs, ecol_s, ew_s, bufB, n);      // agg1 -> fp32
    linear_lorentz<0><<<LGRID, 256, 0, stream>>>(bufB, wt2, b2, s2, bufH, n);       // norm+relu+L2 -> fp16
    gather_logits_kernel<<<GGRID, 256, 0, stream>>>(bufH, rs, ecol_s, ew_s, cls, cb, outp, n); // agg2+logits
}